// Round 14
// baseline (294.799 us; speedup 1.0000x reference)
//
#include <hip/hip_runtime.h>

#define N_NODES 50000
#define N_EDGES 600000
#define D 128   // D_IN == HID
#define NCLS 64
#define SRC_HALF 25000   // src-range phase split: active gather slice 3.2MB < 4MiB per-XCD L2

// Binned CSR build over INTERLEAVED row space: row(v,g) = 2v+g, rows 0..2N-1.
// A node's two graph ranges are adjacent: [off[2v],off[2v+1]) u [off[2v+1],off[2v+2]).
#define BIN_SHIFT 9
#define BIN_ROWS 512
#define NBINS 196        // ceil(100000/512)
#define BIN_CAP 8192     // mean 6122, sd 78 -> +26 sigma
#define CHUNK 4096       // edges per multisplit block
#define EPT (CHUNK / 256)
#define NCHUNKS 293      // ceil(2E/CHUNK)
#define W12_BLOCKS 17    // 17*256 = 4352 threads for 8256 outputs

// bf16 helpers (tables only; all arithmetic stays f32)
__device__ inline unsigned short f2bf(float f) {
  unsigned int u = __float_as_uint(f);
  unsigned int r = (u + 0x7FFF + ((u >> 16) & 1)) >> 16;  // RNE
  return (unsigned short)r;
}
__device__ inline float bf2f(unsigned short b) {
  return __uint_as_float(((unsigned int)b) << 16);
}

// ============ K1: multisplit scatter (blocks < NCHUNKS) + W12/cvec (blocks >= NCHUNKS) ============

__global__ __launch_bounds__(256) void scatter_w12(const int* __restrict__ src1,
                                                   const int* __restrict__ dst1,
                                                   const int* __restrict__ src2,
                                                   const int* __restrict__ dst2,
                                                   int* __restrict__ bincnt,
                                                   int2* __restrict__ binbuf,
                                                   const float* __restrict__ W1,
                                                   const float* __restrict__ W2,
                                                   const float* __restrict__ b1,
                                                   float* __restrict__ W12,
                                                   float* __restrict__ cvec) {
  __shared__ int bcnt[NBINS];
  __shared__ int boff[NBINS];
  __shared__ int gbase[NBINS];
  __shared__ int stmp[256];
  __shared__ int2 stage[CHUNK];

  if (blockIdx.x >= NCHUNKS) {  // ---- w12 part: W12 = W1@W2, cvec = b1@W2 ----
    int gid = (blockIdx.x - NCHUNKS) * 256 + threadIdx.x;
    for (int t = gid; t < D * NCLS + NCLS; t += W12_BLOCKS * 256) {
      if (t < D * NCLS) {
        int i = t >> 6, j = t & 63;
        float s = 0.f;
        for (int k = 0; k < D; ++k) s += W1[i * D + k] * W2[k * NCLS + j];
        W12[t] = s;
      } else {
        int j = t - D * NCLS;
        float s = 0.f;
        for (int k = 0; k < D; ++k) s += b1[k] * W2[k * NCLS + j];
        cvec[j] = s;
      }
    }
    return;
  }

  int base = blockIdx.x * CHUNK;
  int nloc = min(CHUNK, 2 * N_EDGES - base);

  for (int t = threadIdx.x; t < NBINS; t += 256) bcnt[t] = 0;
  __syncthreads();

  int rows[EPT], srcs[EPT], bins[EPT];
#pragma unroll
  for (int k = 0; k < EPT; ++k) {
    int t = threadIdx.x + k * 256;  // coalesced
    rows[k] = -1;
    if (t < nloc) {
      int i = base + t;
      int row, sv;
      if (i < N_EDGES) { row = dst1[i] * 2; sv = src1[i]; }            // graph 1 -> even rows
      else { int e = i - N_EDGES; row = dst2[e] * 2 + 1; sv = src2[e]; }  // graph 2 -> odd rows
      rows[k] = row; srcs[k] = sv;
      bins[k] = row >> BIN_SHIFT;
      atomicAdd(&bcnt[bins[k]], 1);
    }
  }
  __syncthreads();
  {  // exclusive scan bcnt -> boff (NBINS <= 256)
    int tid = threadIdx.x;
    int v = (tid < NBINS) ? bcnt[tid] : 0;
    stmp[tid] = v;
    __syncthreads();
    int x = v;
    for (int o = 1; o < 256; o <<= 1) {
      int y = (tid >= o) ? stmp[tid - o] : 0;
      __syncthreads();
      x += y;
      stmp[tid] = x;
      __syncthreads();
    }
    if (tid < NBINS) boff[tid] = x - v;
  }
  __syncthreads();
  for (int t = threadIdx.x; t < NBINS; t += 256) {  // stash count; init cursor
    gbase[t] = bcnt[t];
    bcnt[t] = boff[t];
  }
  __syncthreads();
#pragma unroll
  for (int k = 0; k < EPT; ++k) {  // rank + place into bin-grouped LDS
    if (rows[k] >= 0) {
      int p = atomicAdd(&bcnt[bins[k]], 1);
      stage[p] = make_int2(rows[k], srcs[k]);
    }
  }
  __syncthreads();
  for (int t = threadIdx.x; t < NBINS; t += 256) {  // one global atomic per bin
    int c = gbase[t];
    if (c > 0) gbase[t] = atomicAdd(&bincnt[t], c);
  }
  __syncthreads();
  for (int j = threadIdx.x; j < nloc; j += 256) {  // flush contiguous runs
    int2 e = stage[j];
    int b = e.x >> BIN_SHIFT;
    int gp = gbase[b] + (j - boff[b]);
    if (gp < BIN_CAP) binbuf[(size_t)b * BIN_CAP + gp] = e;
  }
}

// ============ K2: bin_build (blocks < NBINS) + gemm64 (blocks >= NBINS), 512 threads ============
// (row-space agnostic; unchanged from HW-validated R10/R13 version)

__global__ __launch_bounds__(512) void build_gemm(const int* __restrict__ bincnt,
                                                  const int2* __restrict__ binbuf,
                                                  int* __restrict__ off, int* __restrict__ adj,
                                                  const float* __restrict__ A,
                                                  const float* __restrict__ W,
                                                  unsigned short* __restrict__ C) {
  __shared__ int sh[BIN_ROWS];
  __shared__ int lp[BIN_ROWS];
  __shared__ int stmp[256];
  __shared__ float As[16][65];
  __shared__ float Ws[16][64];

  int tid = threadIdx.x;

  if (blockIdx.x < NBINS) {  // ---- bin_build part ----
    int b = blockIdx.x;
    if (tid < 256) stmp[tid] = (tid < NBINS) ? bincnt[tid] : 0;
    __syncthreads();
    int x = (tid < 256) ? stmp[tid] : 0;
    for (int o = 1; o < 256; o <<= 1) {
      int y = (tid < 256 && tid >= o) ? stmp[tid - o] : 0;
      __syncthreads();
      x += y;
      if (tid < 256) stmp[tid] = x;
      __syncthreads();
    }
    int base = (b == 0) ? 0 : stmp[b - 1];   // exclusive prefix (stmp inclusive)
    if (b == 0 && tid == 0) off[2 * N_NODES] = stmp[NBINS - 1];  // total == 2E
    int n = min(bincnt[b], BIN_CAP);

    sh[tid] = 0;
    __syncthreads();
    for (int t = tid; t < n; t += 512) {
      int row = binbuf[(size_t)b * BIN_CAP + t].x;
      atomicAdd(&sh[row & (BIN_ROWS - 1)], 1);
    }
    __syncthreads();
    int v = sh[tid];
    int xx = v;
    for (int o = 1; o < BIN_ROWS; o <<= 1) {   // validated 512-wide scan
      int y = (tid >= o) ? sh[tid - o] : 0;
      __syncthreads();
      xx += y;
      sh[tid] = xx;
      __syncthreads();
    }
    lp[tid] = xx - v;                           // exclusive local prefix
    int row = (b << BIN_SHIFT) + tid;
    if (row < 2 * N_NODES) off[row] = base + lp[tid];
    __syncthreads();
    sh[tid] = lp[tid];                          // cursors
    __syncthreads();
    for (int t = tid; t < n; t += 512) {
      int2 e = binbuf[(size_t)b * BIN_CAP + t];
      int p = atomicAdd(&sh[e.x & (BIN_ROWS - 1)], 1);
      adj[base + p] = e.y;                      // bin-local contiguous window
    }
    return;
  }

  // ---- gemm64 part: C[M,64] = bf16(A[M,128] @ W[128,64]) ----
  constexpr int BM = 64, BK = 16, BN = 64;
  constexpr int TCOL = BN / 16;  // 4
  const int tx = tid & 15;
  const int ty = (tid >> 4) & 15;
  const int row0 = (blockIdx.x - NBINS) * BM;
  float acc[4][TCOL];
#pragma unroll
  for (int r = 0; r < 4; ++r)
#pragma unroll
    for (int c = 0; c < TCOL; ++c) acc[r][c] = 0.f;

  for (int k0 = 0; k0 < D; k0 += BK) {          // uniform trip for all 512 threads
    if (tid < 256) {  // stage A tile transposed: As[k][row]
      int r = tid >> 2;
      int kq = (tid & 3) << 2;
      int gr = row0 + r;
      float4 v = make_float4(0.f, 0.f, 0.f, 0.f);
      if (gr < N_NODES) v = *(const float4*)(A + (size_t)gr * D + k0 + kq);
      As[kq + 0][r] = v.x;
      As[kq + 1][r] = v.y;
      As[kq + 2][r] = v.z;
      As[kq + 3][r] = v.w;
    }
    if (tid < 256) {  // stage W tile: Ws[k][c]
      int k = tid >> 4;
      int c4 = (tid & 15) << 2;
      *(float4*)(&Ws[k][c4]) = *(const float4*)(W + (size_t)(k0 + k) * BN + c4);
    }
    __syncthreads();
    if (tid < 256) {
#pragma unroll
      for (int k = 0; k < BK; ++k) {
        float a[4];
#pragma unroll
        for (int r = 0; r < 4; ++r) a[r] = As[k][ty * 4 + r];
        float w[TCOL];
#pragma unroll
        for (int c = 0; c < TCOL; ++c) w[c] = Ws[k][tx * TCOL + c];
#pragma unroll
        for (int r = 0; r < 4; ++r)
#pragma unroll
          for (int c = 0; c < TCOL; ++c) acc[r][c] += a[r] * w[c];
      }
    }
    __syncthreads();
  }
  if (tid < 256) {
#pragma unroll
    for (int r = 0; r < 4; ++r) {
      int gr = row0 + ty * 4 + r;
      if (gr < N_NODES) {
        ushort4 pk;
        pk.x = f2bf(acc[r][0]);
        pk.y = f2bf(acc[r][1]);
        pk.z = f2bf(acc[r][2]);
        pk.w = f2bf(acc[r][3]);
        *(ushort4*)(C + (size_t)gr * BN + tx * TCOL) = pk;
      }
    }
  }
}

// ============ 64-wide aggregation: merged ranges + 8-deep unroll + src-phase split ============
// Two sweeps over each node's adjacency: phase 0 gathers only src<SRC_HALF
// (active X slice 3.2MB fits 4MiB per-XCD L2), phase 1 the rest. Broadcast
// indices are wave-uniform -> phase test is a uniform branch, skipped loads
// issue no memory traffic. Weight: (base+i<mid ? 0.9 : 0.8), wave-uniform.
// FIN: Y += 1.7*s(v)*c + 1.7*b2, s(v) = 1.7 + 0.9*deg1 + 0.8*deg2.

template <int FIN, int OUT_BF16>
__global__ __launch_bounds__(256) void agg64_kernel(const unsigned short* __restrict__ X,
                                                    const int* __restrict__ off,
                                                    const int* __restrict__ adj,
                                                    const float* __restrict__ cvec,
                                                    const float* __restrict__ b2,
                                                    void* __restrict__ Yv) {
  int wid = (blockIdx.x * blockDim.x + threadIdx.x) >> 6;  // node
  if (wid >= N_NODES) return;
  int lane = threadIdx.x & 63;

  float self = bf2f(X[(size_t)wid * 64 + lane]);

  int s = off[2 * wid], mid = off[2 * wid + 1], e = off[2 * wid + 2];

  float a0 = 0.f, a1 = 0.f, a2 = 0.f, a3 = 0.f;
  float a4 = 0.f, a5 = 0.f, a6 = 0.f, a7 = 0.f;
#pragma unroll
  for (int ph = 0; ph < 2; ++ph) {
    const bool low = (ph == 0);
    for (int base = s; base < e; base += 64) {
      int m = e - base;
      if (m > 64) m = 64;
      int idx = (lane < m) ? adj[base + lane] : 0;  // coalesced index batch
      int i = 0;
      for (; i + 8 <= m; i += 8) {                  // uniform trip; in-phase loads overlap
        int n0 = __shfl(idx, i + 0);
        int n1 = __shfl(idx, i + 1);
        int n2 = __shfl(idx, i + 2);
        int n3 = __shfl(idx, i + 3);
        int n4 = __shfl(idx, i + 4);
        int n5 = __shfl(idx, i + 5);
        int n6 = __shfl(idx, i + 6);
        int n7 = __shfl(idx, i + 7);
        float w0 = (base + i + 0 < mid) ? 0.9f : 0.8f;   // wave-uniform
        float w1 = (base + i + 1 < mid) ? 0.9f : 0.8f;
        float w2 = (base + i + 2 < mid) ? 0.9f : 0.8f;
        float w3 = (base + i + 3 < mid) ? 0.9f : 0.8f;
        float w4 = (base + i + 4 < mid) ? 0.9f : 0.8f;
        float w5 = (base + i + 5 < mid) ? 0.9f : 0.8f;
        float w6 = (base + i + 6 < mid) ? 0.9f : 0.8f;
        float w7 = (base + i + 7 < mid) ? 0.9f : 0.8f;
        if ((n0 < SRC_HALF) == low) a0 += w0 * bf2f(X[(size_t)n0 * 64 + lane]);
        if ((n1 < SRC_HALF) == low) a1 += w1 * bf2f(X[(size_t)n1 * 64 + lane]);
        if ((n2 < SRC_HALF) == low) a2 += w2 * bf2f(X[(size_t)n2 * 64 + lane]);
        if ((n3 < SRC_HALF) == low) a3 += w3 * bf2f(X[(size_t)n3 * 64 + lane]);
        if ((n4 < SRC_HALF) == low) a4 += w4 * bf2f(X[(size_t)n4 * 64 + lane]);
        if ((n5 < SRC_HALF) == low) a5 += w5 * bf2f(X[(size_t)n5 * 64 + lane]);
        if ((n6 < SRC_HALF) == low) a6 += w6 * bf2f(X[(size_t)n6 * 64 + lane]);
        if ((n7 < SRC_HALF) == low) a7 += w7 * bf2f(X[(size_t)n7 * 64 + lane]);
      }
      for (; i < m; ++i) {                          // uniform tail
        int n0 = __shfl(idx, i);
        if ((n0 < SRC_HALF) == low) {
          float w = (base + i < mid) ? 0.9f : 0.8f;
          a0 += w * bf2f(X[(size_t)n0 * 64 + lane]);
        }
      }
    }
  }
  float acc = ((a0 + a1) + (a2 + a3)) + ((a4 + a5) + (a6 + a7));
  float y = 1.7f * self + acc;
  if (FIN) {
    float sv = 1.7f * (1.7f + 0.9f * (float)(mid - s) + 0.8f * (float)(e - mid));
    y += sv * cvec[lane] + 1.7f * b2[lane];
  }
  if (OUT_BF16) {
    ((unsigned short*)Yv)[(size_t)wid * 64 + lane] = f2bf(y);
  } else {
    ((float*)Yv)[(size_t)wid * 64 + lane] = y;
  }
}

// ============ launch ============
// Math: gates == 1 (softmax over size-1 axis), so with L(X) = 1.7X + 0.9*A1X + 0.8*A2X:
//   out = L(L(F @ W12)) + 1.7*s(v)*(b1@W2) + 1.7*b2    (pushdown exact; validated R5)
// 5 dispatches: memset -> scatter+w12 -> bin_build+gemm -> agg -> agg.

extern "C" void kernel_launch(void* const* d_in, const int* in_sizes, int n_in,
                              void* d_out, int out_size, void* d_ws, size_t ws_size,
                              hipStream_t stream) {
  const float* F  = (const float*)d_in[0];
  const int* src1 = (const int*)d_in[1];
  const int* dst1 = (const int*)d_in[2];
  const int* src2 = (const int*)d_in[3];
  const int* dst2 = (const int*)d_in[4];
  const float* W1 = (const float*)d_in[5];
  const float* b1 = (const float*)d_in[6];
  const float* W2 = (const float*)d_in[7];
  const float* b2 = (const float*)d_in[8];
  // d_in[9..16] (gate weights) are dead: softmax over a size-1 axis == 1.
  float* out = (float*)d_out;

  char* ws = (char*)d_ws;
  auto aln = [](size_t x) { return (x + 255) & ~(size_t)255; };
  size_t o = 0;
  int* bincnt  = (int*)(ws + o); o = aln(o + (size_t)NBINS * 4);
  int* off     = (int*)(ws + o); o = aln(o + ((size_t)2 * N_NODES + 1) * 4);
  int2* binbuf = (int2*)(ws + o); o = aln(o + (size_t)NBINS * BIN_CAP * 8);
  int* adj     = (int*)(ws + o); o = aln(o + (size_t)2 * N_EDGES * 4);
  float* W12   = (float*)(ws + o); o = aln(o + (size_t)D * NCLS * 4);
  float* cvec  = (float*)(ws + o); o = aln(o + NCLS * 4);
  unsigned short* H = (unsigned short*)(ws + o); o = aln(o + (size_t)N_NODES * NCLS * 2);
  unsigned short* T = (unsigned short*)(ws + o); o = aln(o + (size_t)N_NODES * NCLS * 2);
  (void)ws_size;  // ~31 MB used

  hipMemsetAsync(bincnt, 0, (size_t)NBINS * 4, stream);
  // K1: scatter into bins (interleaved rows) + W12/cvec
  scatter_w12<<<NCHUNKS + W12_BLOCKS, 256, 0, stream>>>(src1, dst1, src2, dst2,
                                                        bincnt, binbuf, W1, W2, b1, W12, cvec);
  // K2: per-bin CSR build (off, adj) + H = bf16(F @ W12)
  build_gemm<<<NBINS + (N_NODES + 63) / 64, 512, 0, stream>>>(bincnt, binbuf, off, adj,
                                                              F, W12, H);
  // T = bf16(L(H))
  agg64_kernel<0, 1><<<N_NODES / 4, 256, 0, stream>>>(H, off, adj, cvec, b2, T);
  // out = L(T) + 1.7*s(v)*c + 1.7*b2   (f32)
  agg64_kernel<1, 0><<<N_NODES / 4, 256, 0, stream>>>(T, off, adj, cvec, b2, out);
}